// Round 4
// baseline (64.939 us; speedup 1.0000x reference)
//
#include <hip/hip_runtime.h>

// Floyd-Steinberg halftoning, fused: gray conversion + per-8x8-tile error
// diffusion (transposed orientation, matching reference's swapaxes) + 3-channel
// broadcast + zero-mask + /255.
//
// One thread per 8x8 tile (131072 tiles -> 512 blocks of 256 -> 2 waves/SIMD,
// grid-capped). Occupancy is grid-limited, so we spend VGPRs on memory-level
// parallelism instead: __launch_bounds__(256,2) allows 256 VGPRs and ALL 48
// float4 loads are issued up front (one latency exposure). Output stores are
// non-temporal (via native ext_vector_type -- HIP's float4 class is rejected
// by the builtin) so the 96 MiB input stays Infinity-Cache-resident across
// graph replays.

#define IMG_H 1024
#define IMG_W 1024
#define NCH   3

typedef float v4f __attribute__((ext_vector_type(4)));

__global__ __launch_bounds__(256, 2)
void fs_halftone_kernel(const float* __restrict__ in, float* __restrict__ out,
                        int n_imgs) {
#pragma clang fp contract(off)
    const int tiles_w = IMG_W / 8;                 // 128
    const int tiles_per_img = tiles_w * (IMG_H / 8);

    int tile = blockIdx.x * blockDim.x + threadIdx.x;
    int b  = tile / tiles_per_img;
    if (b >= n_imgs) return;
    int t  = tile % tiles_per_img;
    int th = t / tiles_w;
    int tw = t % tiles_w;

    const size_t imgstride = (size_t)IMG_H * IMG_W;
    const size_t tile_off  = (size_t)(th * 8) * IMG_W + (size_t)(tw * 8);
    const float* base = in  + (size_t)b * NCH * imgstride + tile_off;
    float*      obase = out + (size_t)b * NCH * imgstride + tile_off;

    // ---- issue ALL 48 float4 loads up front, in consume order ----
    v4f l0[8][2], l1[8][2], l2[8][2];
#pragma unroll
    for (int r = 0; r < 8; ++r) {
        l0[r][0] = *(const v4f*)(base + 0 * imgstride + (size_t)r * IMG_W);
        l0[r][1] = *(const v4f*)(base + 0 * imgstride + (size_t)r * IMG_W + 4);
    }
#pragma unroll
    for (int r = 0; r < 8; ++r) {
        l1[r][0] = *(const v4f*)(base + 1 * imgstride + (size_t)r * IMG_W);
        l1[r][1] = *(const v4f*)(base + 1 * imgstride + (size_t)r * IMG_W + 4);
    }
#pragma unroll
    for (int r = 0; r < 8; ++r) {
        l2[r][0] = *(const v4f*)(base + 2 * imgstride + (size_t)r * IMG_W);
        l2[r][1] = *(const v4f*)(base + 2 * imgstride + (size_t)r * IMG_W + 4);
    }

    // ---- consume ch0/ch1 (oldest loads) -> partial gray + masks; ch2 loads
    //      may still be in flight ----
    float g[64];
    unsigned long long zm0 = 0ull, zm1 = 0ull, zm2 = 0ull;
#pragma unroll
    for (int r = 0; r < 8; ++r) {
#pragma unroll
        for (int h = 0; h < 2; ++h) {
#pragma unroll
            for (int k = 0; k < 4; ++k) {
                int c = h * 4 + k;
                int idx = r * 8 + c;
                float s0 = l0[r][h][k] * 255.0f;
                float s1 = l1[r][h][k] * 255.0f;
                if (s0 == 0.0f) zm0 |= 1ull << idx;
                if (s1 == 0.0f) zm1 |= 1ull << idx;
                g[idx] = (0.114f * s0) + (0.587f * s1);
            }
        }
    }
#pragma unroll
    for (int r = 0; r < 8; ++r) {
#pragma unroll
        for (int h = 0; h < 2; ++h) {
#pragma unroll
            for (int k = 0; k < 4; ++k) {
                int c = h * 4 + k;
                int idx = r * 8 + c;
                float s2 = l2[r][h][k] * 255.0f;
                if (s2 == 0.0f) zm2 |= 1ull << idx;
                g[idx] = g[idx] + (0.299f * s2);   // ((0.114 s0 + 0.587 s1) + 0.299 s2)
            }
        }
    }

    // ---- Floyd-Steinberg on the TRANSPOSED tile.
    // FS row i == original column i; FS col j == original row j.
    float nrow[8];
#pragma unroll
    for (int j = 0; j < 8; ++j) nrow[j] = 0.0f;

    unsigned long long hbits = 0ull;  // bit (j*8+i): halftone==255 at orig (j,i)

#pragma unroll
    for (int i = 0; i < 8; ++i) {          // FS rows (original columns)
        float errs[8];
        float er = 0.0f;                   // err_right carry
#pragma unroll
        for (int j = 0; j < 8; ++j) {      // serial pixel scan (original rows)
            float px  = g[j * 8 + i] + nrow[j];  // row + next_row_err
            float old = px + er;                 // + err_right
            bool  on  = old > 127.0f;
            float nw  = on ? 255.0f : 0.0f;
            float e   = old - nw;
            er = e * 0.4375f;                    // 7/16
            errs[j] = e;
            if (on) hbits |= 1ull << (j * 8 + i);
        }
#pragma unroll
        for (int j = 0; j < 8; ++j) {
            float en = (j < 7) ? errs[j + 1] : 0.0f;
            float ep = (j > 0) ? errs[j - 1] : 0.0f;
            nrow[j] = ((0.3125f * errs[j]) + (0.1875f * en)) + (0.0625f * ep);
        }
    }

    // ---- write 3 channels, non-temporal: out = (in==0) ? 0 : ht/255 ----
#pragma unroll
    for (int ch = 0; ch < 3; ++ch) {
        unsigned long long zm = (ch == 0) ? zm0 : ((ch == 1) ? zm1 : zm2);
#pragma unroll
        for (int r = 0; r < 8; ++r) {
            v4f v0, v1;
#pragma unroll
            for (int c = 0; c < 8; ++c) {
                int idx = r * 8 + c;
                bool on = (hbits >> idx) & 1ull;
                bool z  = (zm    >> idx) & 1ull;
                float val = (on && !z) ? 1.0f : 0.0f;
                if (c < 4) v0[c] = val; else v1[c - 4] = val;
            }
            __builtin_nontemporal_store(v0,
                (v4f*)(obase + ch * imgstride + (size_t)r * IMG_W));
            __builtin_nontemporal_store(v1,
                (v4f*)(obase + ch * imgstride + (size_t)r * IMG_W + 4));
        }
    }
}

extern "C" void kernel_launch(void* const* d_in, const int* in_sizes, int n_in,
                              void* d_out, int out_size, void* d_ws, size_t ws_size,
                              hipStream_t stream) {
    const float* in  = (const float*)d_in[0];
    float*       out = (float*)d_out;

    int n_imgs = in_sizes[0] / (NCH * IMG_H * IMG_W);  // 8
    int total_tiles = n_imgs * (IMG_H / 8) * (IMG_W / 8);
    int block = 256;
    int grid = (total_tiles + block - 1) / block;
    fs_halftone_kernel<<<grid, block, 0, stream>>>(in, out, n_imgs);
}

// Round 5
// 46.946 us; speedup vs baseline: 1.3833x; 1.3833x over previous
//
#include <hip/hip_runtime.h>

// Floyd-Steinberg halftoning, fused + software-pipelined across 2 tiles/thread.
//
// R2 analysis: with 1 tile/thread all 2048 waves run read->compute->write in
// lockstep => bulk-synchronous phases, no read/write stream overlap (42 us vs
// 30.5 us 192MB-mixed floor). Here each thread owns tiles (tid, tid+half):
//   load A -> gray A -> ISSUE loads B -> FS A (VALU hides B latency)
//   -> store A (overlaps B in-flight) -> gray/FS/store B.
// Tile output state is only 4 u64 bitmasks, so the pipeline is register-cheap.
// __launch_bounds__(256,1): 1 wave/SIMD, up to 512 VGPRs for 48 in-flight loads.
// Regular stores (R4: non-temporal stores increased WRITE_SIZE 100->139MB and
// regressed 42->65 us).

#define IMG_H 1024
#define IMG_W 1024
#define NCH   3

typedef float v4f __attribute__((ext_vector_type(4)));

#pragma clang fp contract(off)

__device__ __forceinline__ void gray_masks(const v4f (&l0)[8][2], const v4f (&l1)[8][2],
                                           const v4f (&l2)[8][2], float (&g)[64],
                                           unsigned long long& zm0, unsigned long long& zm1,
                                           unsigned long long& zm2) {
#pragma clang fp contract(off)
    zm0 = zm1 = zm2 = 0ull;
#pragma unroll
    for (int r = 0; r < 8; ++r) {
#pragma unroll
        for (int h = 0; h < 2; ++h) {
#pragma unroll
            for (int k = 0; k < 4; ++k) {
                int c = h * 4 + k;
                int idx = r * 8 + c;
                float s0 = l0[r][h][k] * 255.0f;
                float s1 = l1[r][h][k] * 255.0f;
                float s2 = l2[r][h][k] * 255.0f;
                if (s0 == 0.0f) zm0 |= 1ull << idx;
                if (s1 == 0.0f) zm1 |= 1ull << idx;
                if (s2 == 0.0f) zm2 |= 1ull << idx;
                // exact reference order: (0.114*s0 + 0.587*s1) + 0.299*s2, no FMA
                g[idx] = ((0.114f * s0) + (0.587f * s1)) + (0.299f * s2);
            }
        }
    }
}

// FS on the TRANSPOSED tile (matches reference's swapaxes orientation).
// FS row i == original column i; FS col j == original row j.
__device__ __forceinline__ unsigned long long run_fs(const float (&g)[64]) {
#pragma clang fp contract(off)
    float nrow[8];
#pragma unroll
    for (int j = 0; j < 8; ++j) nrow[j] = 0.0f;
    unsigned long long hbits = 0ull;  // bit (j*8+i): halftone==255 at orig (j,i)
#pragma unroll
    for (int i = 0; i < 8; ++i) {
        float errs[8];
        float er = 0.0f;
#pragma unroll
        for (int j = 0; j < 8; ++j) {
            float px  = g[j * 8 + i] + nrow[j];
            float old = px + er;
            bool  on  = old > 127.0f;
            float nw  = on ? 255.0f : 0.0f;
            float e   = old - nw;
            er = e * 0.4375f;                    // 7/16
            errs[j] = e;
            if (on) hbits |= 1ull << (j * 8 + i);
        }
#pragma unroll
        for (int j = 0; j < 8; ++j) {
            float en = (j < 7) ? errs[j + 1] : 0.0f;
            float ep = (j > 0) ? errs[j - 1] : 0.0f;
            nrow[j] = ((0.3125f * errs[j]) + (0.1875f * en)) + (0.0625f * ep);
        }
    }
    return hbits;
}

__device__ __forceinline__ void store_tile(float* obase, size_t imgstride,
                                           unsigned long long hbits,
                                           unsigned long long zm0, unsigned long long zm1,
                                           unsigned long long zm2) {
#pragma unroll
    for (int ch = 0; ch < 3; ++ch) {
        unsigned long long zm = (ch == 0) ? zm0 : ((ch == 1) ? zm1 : zm2);
#pragma unroll
        for (int r = 0; r < 8; ++r) {
            v4f v0, v1;
#pragma unroll
            for (int c = 0; c < 8; ++c) {
                int idx = r * 8 + c;
                bool on = (hbits >> idx) & 1ull;
                bool z  = (zm    >> idx) & 1ull;
                float val = (on && !z) ? 1.0f : 0.0f;
                if (c < 4) v0[c] = val; else v1[c - 4] = val;
            }
            *(v4f*)(obase + ch * imgstride + (size_t)r * IMG_W)     = v0;
            *(v4f*)(obase + ch * imgstride + (size_t)r * IMG_W + 4) = v1;
        }
    }
}

__device__ __forceinline__ void load_tile(const float* base, size_t imgstride,
                                          v4f (&l0)[8][2], v4f (&l1)[8][2], v4f (&l2)[8][2]) {
#pragma unroll
    for (int r = 0; r < 8; ++r) {
        l0[r][0] = *(const v4f*)(base + 0 * imgstride + (size_t)r * IMG_W);
        l0[r][1] = *(const v4f*)(base + 0 * imgstride + (size_t)r * IMG_W + 4);
    }
#pragma unroll
    for (int r = 0; r < 8; ++r) {
        l1[r][0] = *(const v4f*)(base + 1 * imgstride + (size_t)r * IMG_W);
        l1[r][1] = *(const v4f*)(base + 1 * imgstride + (size_t)r * IMG_W + 4);
    }
#pragma unroll
    for (int r = 0; r < 8; ++r) {
        l2[r][0] = *(const v4f*)(base + 2 * imgstride + (size_t)r * IMG_W);
        l2[r][1] = *(const v4f*)(base + 2 * imgstride + (size_t)r * IMG_W + 4);
    }
}

__global__ __launch_bounds__(256, 1)
void fs_halftone_kernel(const float* __restrict__ in, float* __restrict__ out,
                        int n_imgs) {
#pragma clang fp contract(off)
    const int tiles_w = IMG_W / 8;                 // 128
    const int tiles_per_img = tiles_w * (IMG_H / 8);
    const int total_tiles = n_imgs * tiles_per_img;
    const int half = (total_tiles + 1) / 2;

    int tid = blockIdx.x * blockDim.x + threadIdx.x;
    if (tid >= half) return;

    const size_t imgstride = (size_t)IMG_H * IMG_W;

    // tile A = tid, tile B = tid + half
    int tA = tid;
    int bA = tA / tiles_per_img, rA = tA % tiles_per_img;
    const float* baseA = in  + (size_t)bA * NCH * imgstride
                             + (size_t)(rA / tiles_w * 8) * IMG_W + (size_t)(rA % tiles_w * 8);
    float* obaseA      = out + (size_t)bA * NCH * imgstride
                             + (size_t)(rA / tiles_w * 8) * IMG_W + (size_t)(rA % tiles_w * 8);

    int tB = tid + half;
    bool hasB = tB < total_tiles;
    int tBc = hasB ? tB : tA;
    int bB = tBc / tiles_per_img, rB = tBc % tiles_per_img;
    const float* baseB = in  + (size_t)bB * NCH * imgstride
                             + (size_t)(rB / tiles_w * 8) * IMG_W + (size_t)(rB % tiles_w * 8);
    float* obaseB      = out + (size_t)bB * NCH * imgstride
                             + (size_t)(rB / tiles_w * 8) * IMG_W + (size_t)(rB % tiles_w * 8);

    // ---- pipeline ----
    v4f a0[8][2], a1[8][2], a2[8][2];
    load_tile(baseA, imgstride, a0, a1, a2);               // loads A in flight

    float gA[64];
    unsigned long long zA0, zA1, zA2;
    gray_masks(a0, a1, a2, gA, zA0, zA1, zA2);             // waits A, frees a*

    v4f b0[8][2], b1[8][2], b2[8][2];
    load_tile(baseB, imgstride, b0, b1, b2);               // ISSUE loads B early

    unsigned long long hA = run_fs(gA);                    // VALU hides B latency

    store_tile(obaseA, imgstride, hA, zA0, zA1, zA2);      // stores overlap B loads

    if (hasB) {
        float gB[64];
        unsigned long long zB0, zB1, zB2;
        gray_masks(b0, b1, b2, gB, zB0, zB1, zB2);         // waits B
        unsigned long long hB = run_fs(gB);
        store_tile(obaseB, imgstride, hB, zB0, zB1, zB2);
    }
}

extern "C" void kernel_launch(void* const* d_in, const int* in_sizes, int n_in,
                              void* d_out, int out_size, void* d_ws, size_t ws_size,
                              hipStream_t stream) {
    const float* in  = (const float*)d_in[0];
    float*       out = (float*)d_out;

    int n_imgs = in_sizes[0] / (NCH * IMG_H * IMG_W);  // 8
    int total_tiles = n_imgs * (IMG_H / 8) * (IMG_W / 8);
    int half = (total_tiles + 1) / 2;                  // 2 tiles per thread
    int block = 256;
    int grid = (half + block - 1) / block;
    fs_halftone_kernel<<<grid, block, 0, stream>>>(in, out, n_imgs);
}